// Round 14
// baseline (72.677 us; speedup 1.0000x reference)
//
#include <hip/hip_runtime.h>
#include <math.h>

// Problem constants
constexpr int LL = 4096;
constexpr int CC = 256;
constexpr int MM = 32768;  // N*L rows

typedef unsigned int u32;
typedef unsigned short u16;
typedef __attribute__((ext_vector_type(8))) short bf16x8;
typedef __attribute__((ext_vector_type(4))) float f32x4;

__device__ __forceinline__ u16 f2b(float f) {   // RNE fp32->bf16
    u32 u = __float_as_uint(f);
    u32 r = (u + 0x7fffu + ((u >> 16) & 1u)) >> 16;
    return (u16)r;
}
__device__ __forceinline__ u32 pack2(float a, float b) {  // RNE pair
    return (u32)f2b(a) | ((u32)f2b(b) << 16);
}

// async global->LDS DMA, 16B per lane; LDS dest = wave-uniform base + lane*16
__device__ __forceinline__ void gl_lds16(const u16* g, u16* l) {
    __builtin_amdgcn_global_load_lds(
        (const __attribute__((address_space(1))) unsigned int*)g,
        (__attribute__((address_space(3))) unsigned int*)l, 16, 0, 0);
}

// ---------------------------------------------------------------------------
// prep_w: bf16 transposed weights (separate launch; conv_gemm needs Wt_in).
// ---------------------------------------------------------------------------
__global__ __launch_bounds__(256) void prep_w(
    const float* __restrict__ W_in, const float* __restrict__ W_out,
    const float* __restrict__ W_off, const float* __restrict__ W_mask,
    u16* __restrict__ Wt_in, u16* __restrict__ Wt_out, u16* __restrict__ Wcomb)
{
    const int b = blockIdx.x, t = threadIdx.x;
    if (b < 256) {
        Wt_in[b * 256 + t]  = f2b(W_in[t * 256 + b]);
        Wt_out[b * 256 + t] = f2b(W_out[t * 256 + b]);
    } else {
        const int j = b - 256;  // 0..47
        const float v = (j < 24) ? W_off[t * 24 + j] : W_mask[t * 24 + (j - 24)];
        Wcomb[j * 256 + t] = f2b(v);
    }
}

// ---------------------------------------------------------------------------
// conv_gemm: heterogeneous overlap kernel, LB(256,2) so the gemm path gets
// full VGPR budget (r9's failure was LB(256,3) -> 68 VGPR strangulation).
//  blocks [0,512):    gemm1 (r13 body): x_proj = bf16(x)@Wt_in^T + b_in,
//                     m97 structure, XCD swizzle (XCD k owns sequence k).
//  blocks [512,8704): conv+LN+GELU (r13 body), XCD-aligned remap.
// gemm blocks dispatch first; conv streams behind on complementary pipes.
// ---------------------------------------------------------------------------
__global__ __launch_bounds__(256, 2) void conv_gemm(
    const float* __restrict__ x, const u16* __restrict__ Wt_in,
    const float* __restrict__ b_in, u16* __restrict__ xprojb,
    const float* __restrict__ cw, const float* __restrict__ cbias,
    const float* __restrict__ lng, const float* __restrict__ lnb,
    u16* __restrict__ xf)
{
    __shared__ u16 As[2][128 * 32];
    __shared__ u16 Bs[2][128 * 32];

    const int bid = blockIdx.x;
    const int t = threadIdx.x;

    if (bid >= 512) {
        // ---------------- conv path (r13 body, XCD-aligned) ----------------
        const int c = bid - 512;                       // 0..8191
        const int i = ((c & 7) << 10) | (c >> 3);      // XCD c%8 -> sequence c%8

        const int wave = t >> 6;
        const int lane = t & 63;
        const int nl = (i << 2) + wave;
        const int l = nl & (LL - 1);
        const int c0 = lane << 2;
        const size_t base = (size_t)nl * CC + c0;

        float4 xc = *(const float4*)&x[base];
        float4 xm = make_float4(0.f, 0.f, 0.f, 0.f);
        float4 xp = make_float4(0.f, 0.f, 0.f, 0.f);
        if (l > 0)      xm = *(const float4*)&x[base - CC];
        if (l < LL - 1) xp = *(const float4*)&x[base + CC];

        float xmv[4] = {xm.x, xm.y, xm.z, xm.w};
        float xcv[4] = {xc.x, xc.y, xc.z, xc.w};
        float xpv[4] = {xp.x, xp.y, xp.z, xp.w};

        float y[4];
        float sum = 0.f, sq = 0.f;
#pragma unroll
        for (int j = 0; j < 4; ++j) {
            const int ch = c0 + j;
            float v = fmaf(xmv[j], cw[ch * 3 + 0],
                      fmaf(xcv[j], cw[ch * 3 + 1],
                      fmaf(xpv[j], cw[ch * 3 + 2], cbias[ch])));
            y[j] = v;
            sum += v;
            sq  += v * v;
        }
#pragma unroll
        for (int off = 32; off > 0; off >>= 1) {
            sum += __shfl_xor(sum, off);
            sq  += __shfl_xor(sq, off);
        }
        const float mu  = sum * (1.f / CC);
        const float var = sq * (1.f / CC) - mu * mu;
        const float rs  = rsqrtf(var + 1e-6f);

        ushort4 o;
        float ov[4];
#pragma unroll
        for (int j = 0; j < 4; ++j) {
            const int ch = c0 + j;
            const float tn = (y[j] - mu) * rs * lng[ch] + lnb[ch];
            ov[j] = 0.5f * tn * (1.f + erff(tn * 0.70710678118654752f));
        }
        o.x = f2b(ov[0]); o.y = f2b(ov[1]); o.z = f2b(ov[2]); o.w = f2b(ov[3]);
        *(ushort4*)&xf[base] = o;
        return;
    }

    // ---------------- gemm path (r13 body) ----------------
    const int w = t >> 6, lane = t & 63;
    const int lr = lane & 15, lk = lane >> 4;
    const int wm = w >> 1, wn = w & 1;

    const int d = bid;                     // 0..511
    const int m_t = (d & 7) * 32 + (d >> 4);
    const int n_t = (d >> 3) & 1;
    const int m0 = m_t * 128, n0 = n_t * 128;

    const int srow = lane >> 2;
    const int scol = (lane & 3) * 8;       // k elements
    const int arow = t >> 1;
    const int akh = (t & 1) * 16;

    f32x4 acc[4][4];
#pragma unroll
    for (int i = 0; i < 4; ++i)
#pragma unroll
        for (int j = 0; j < 4; ++j) acc[i][j] = f32x4{0.f, 0.f, 0.f, 0.f};

    auto STAGE_B = [&](int buf, int kt) {
        const int k0 = kt * 32;
#pragma unroll
        for (int j = 0; j < 2; ++j) {
            const int rr = (w * 2 + j) * 16 + srow;
            gl_lds16(Wt_in + ((size_t)(n0 + rr) << 8) + k0 + scol,
                     &Bs[buf][0] + (w * 2 + j) * 512);
        }
    };
    const float* Abase = x + (size_t)(m0 + arow) * 256 + akh;

    {
        float4 f0 = *(const float4*)(Abase);
        float4 f1 = *(const float4*)(Abase + 4);
        float4 f2 = *(const float4*)(Abase + 8);
        float4 f3 = *(const float4*)(Abase + 12);
        STAGE_B(0, 0);
        u16* dst = &As[0][arow * 32 + akh];
        ((u32*)dst)[0] = pack2(f0.x, f0.y); ((u32*)dst)[1] = pack2(f0.z, f0.w);
        ((u32*)dst)[2] = pack2(f1.x, f1.y); ((u32*)dst)[3] = pack2(f1.z, f1.w);
        ((u32*)dst)[4] = pack2(f2.x, f2.y); ((u32*)dst)[5] = pack2(f2.z, f2.w);
        ((u32*)dst)[6] = pack2(f3.x, f3.y); ((u32*)dst)[7] = pack2(f3.z, f3.w);
    }

#pragma unroll
    for (int kt = 0; kt < 8; ++kt) {
        const int cur = kt & 1;
        __syncthreads();                    // stage of buf[cur] complete
        float4 f0, f1, f2, f3;
        if (kt < 7) {                       // issue next-tile loads EARLY
            const float* ap = Abase + (kt + 1) * 32;
            f0 = *(const float4*)(ap);
            f1 = *(const float4*)(ap + 4);
            f2 = *(const float4*)(ap + 8);
            f3 = *(const float4*)(ap + 12);
            STAGE_B(cur ^ 1, kt + 1);
        }
        bf16x8 af[4], bfr[4];
#pragma unroll
        for (int mt = 0; mt < 4; ++mt)
            af[mt] = *(const bf16x8*)&As[cur][(wm * 64 + mt * 16 + lr) * 32 + lk * 8];
#pragma unroll
        for (int nt = 0; nt < 4; ++nt)
            bfr[nt] = *(const bf16x8*)&Bs[cur][(wn * 64 + nt * 16 + lr) * 32 + lk * 8];
#pragma unroll
        for (int mt = 0; mt < 4; ++mt)
#pragma unroll
            for (int nt = 0; nt < 4; ++nt)
                acc[mt][nt] = __builtin_amdgcn_mfma_f32_16x16x32_bf16(
                    af[mt], bfr[nt], acc[mt][nt], 0, 0, 0);
        if (kt < 7) {                       // write LATE (after MFMAs)
            u16* dst = &As[cur ^ 1][arow * 32 + akh];
            ((u32*)dst)[0] = pack2(f0.x, f0.y); ((u32*)dst)[1] = pack2(f0.z, f0.w);
            ((u32*)dst)[2] = pack2(f1.x, f1.y); ((u32*)dst)[3] = pack2(f1.z, f1.w);
            ((u32*)dst)[4] = pack2(f2.x, f2.y); ((u32*)dst)[5] = pack2(f2.z, f2.w);
            ((u32*)dst)[6] = pack2(f3.x, f3.y); ((u32*)dst)[7] = pack2(f3.z, f3.w);
        }
    }

    const int r0 = lk * 4;
#pragma unroll
    for (int nt = 0; nt < 4; ++nt) {
        const int cn = n0 + wn * 64 + nt * 16 + lr;
        const float bv = b_in[cn];
#pragma unroll
        for (int mt = 0; mt < 4; ++mt)
#pragma unroll
            for (int r4 = 0; r4 < 4; ++r4)
                xprojb[(size_t)(m0 + wm * 64 + mt * 16 + r0 + r4) * 256 + cn] =
                    f2b(acc[mt][nt][r4] + bv);
    }
}

// ---------------------------------------------------------------------------
// offmask_gemm: fused { offset/mask MFMA projection + softmax + bilinear
// gather -> LDS } + { final GEMM sampled@W_out + b_out -> fp32 out }.
// 64-row blocks (512), 256 thr, LDS 44KB. XCD-aligned remap (r13).
// ---------------------------------------------------------------------------
__global__ __launch_bounds__(256, 3) void offmask_gemm(
    const u16* __restrict__ xfeatb, const u16* __restrict__ xprojb,
    const u16* __restrict__ Wcomb, const float* __restrict__ boff,
    const float* __restrict__ bmask, const u16* __restrict__ Wt_out,
    const float* __restrict__ b_out, float* __restrict__ out)
{
    __shared__ __align__(16) char s_mem[32768];   // logit then sampled (union)
    __shared__ uint2 s_pack[512 * 3];             // {fp16 a|b, u16 i0|i1} 12KB
    float* logit = (float*)s_mem;                 // [64][50]

    const int t = threadIdx.x;
    const int w = t >> 6, lane = t & 63;
    const int lr = lane & 15, lk8 = (lane >> 4) * 8;
    const int r0 = (lane >> 4) * 4;
    // XCD-aligned remap: blk = (d%8)*64 + d/8  (bijective on 512)
    const int d = blockIdx.x;
    const int blk = ((d & 7) << 6) | (d >> 3);
    const size_t row0 = (size_t)blk * 64;

    // --- Phase 1: projection MFMA -> logits (48 cols per row)
    f32x4 pacc[3];
#pragma unroll
    for (int ct = 0; ct < 3; ++ct) pacc[ct] = f32x4{0.f, 0.f, 0.f, 0.f};
    const u16* fbase = xfeatb + (row0 + w * 16 + lr) * 256;
#pragma unroll
    for (int ks = 0; ks < 8; ++ks) {
        const int ke = ks * 32 + lk8;
        bf16x8 a = *(const bf16x8*)(fbase + ke);
#pragma unroll
        for (int ct = 0; ct < 3; ++ct) {
            bf16x8 bfr = *(const bf16x8*)(Wcomb + (size_t)(ct * 16 + lr) * 256 + ke);
            pacc[ct] = __builtin_amdgcn_mfma_f32_16x16x32_bf16(a, bfr, pacc[ct], 0, 0, 0);
        }
    }
#pragma unroll
    for (int ct = 0; ct < 3; ++ct) {
        const int j = ct * 16 + lr;
        const float bj = (j < 24) ? boff[j] : bmask[j - 24];
#pragma unroll
        for (int r4 = 0; r4 < 4; ++r4)
            logit[(w * 16 + r0 + r4) * 50 + j] = pacc[ct][r4] + bj;
    }
    __syncthreads();

    // --- Phase 2: softmax over K + locations (2 (row,g) pairs per thread)
#pragma unroll
    for (int pi = 0; pi < 2; ++pi) {
        const int pp = pi * 256 + t;        // 0..511
        const int rw = pp >> 3, g = pp & 7;
        const float* lp = &logit[rw * 50];
        const float m0v = lp[24 + g * 3 + 0];
        const float m1v = lp[24 + g * 3 + 1];
        const float m2v = lp[24 + g * 3 + 2];
        const float mx = fmaxf(m0v, fmaxf(m1v, m2v));
        const float e0 = expf(m0v - mx), e1 = expf(m1v - mx), e2 = expf(m2v - mx);
        const float inv = 1.f / (e0 + e1 + e2);
        const float msk[3] = {e0 * inv, e1 * inv, e2 * inv};
        const float lf = (float)((blk & 63) * 64 + rw);
#pragma unroll
        for (int k = 0; k < 3; ++k) {
            const float loc = lf + (float)(k - 1) + lp[g * 3 + k];
            float r = fmodf(loc, (float)LL);
            if (r < 0.f) r += (float)LL;
            const float f0 = floorf(r);
            int i0 = (int)f0;
            i0 = i0 < 0 ? 0 : (i0 > LL - 1 ? LL - 1 : i0);
            const int i1 = i0 + 1;
            const float w1 = r - f0;
            const bool valid = (i1 < LL);
            union { u32 uw; _Float16 h[2]; } uh;
            uh.h[0] = (_Float16)(msk[k] * (1.f - w1));
            uh.h[1] = (_Float16)(valid ? msk[k] * w1 : 0.f);
            const u32 ij = (u32)i0 | ((u32)(valid ? i1 : 0) << 16);
            s_pack[pp * 3 + k] = make_uint2(uh.uw, ij);
        }
    }
    __syncthreads();   // logit reads done; s_mem reusable as sampled tile

    // --- Phase 3: gather-accumulate -> sampled bf16 tile in LDS (swizzled).
    // 8 row-groups x 32 channel-octs; uint4 loads (8 chans/thread).
    {
        const int ig = t >> 5, tc = t & 31;
        const int c0 = tc * 8, g4 = tc >> 2;
        const u16* xpn = xprojb + (size_t)(blk >> 6) * LL * 256;
        const int ibeg = ig * 8;
#pragma unroll 2
        for (int i = ibeg; i < ibeg + 8; ++i) {
            const int bidx = (i * 8 + g4) * 3;
            float v[8] = {0.f, 0.f, 0.f, 0.f, 0.f, 0.f, 0.f, 0.f};
#pragma unroll
            for (int k = 0; k < 3; ++k) {
                const uint2 pk = s_pack[bidx + k];
                union { u32 uw; _Float16 h[2]; } uh; uh.uw = pk.x;
                const float wa = (float)uh.h[0], wb = (float)uh.h[1];
                const int i0 = (int)(pk.y & 0xffffu), i1 = (int)(pk.y >> 16);
                uint4 ua = *(const uint4*)(xpn + (size_t)i0 * 256 + c0);
                uint4 ub = *(const uint4*)(xpn + (size_t)i1 * 256 + c0);
                const u32 au[4] = {ua.x, ua.y, ua.z, ua.w};
                const u32 bu[4] = {ub.x, ub.y, ub.z, ub.w};
#pragma unroll
                for (int j = 0; j < 4; ++j) {
                    v[2 * j]     = fmaf(wa, __uint_as_float(au[j] << 16),
                                   fmaf(wb, __uint_as_float(bu[j] << 16), v[2 * j]));
                    v[2 * j + 1] = fmaf(wa, __uint_as_float(au[j] & 0xffff0000u),
                                   fmaf(wb, __uint_as_float(bu[j] & 0xffff0000u), v[2 * j + 1]));
                }
            }
            uint4 wd;
            wd.x = pack2(v[0], v[1]); wd.y = pack2(v[2], v[3]);
            wd.z = pack2(v[4], v[5]); wd.w = pack2(v[6], v[7]);
            const int addr = (i * 512 + tc * 16) ^ ((i & 7) << 4);
            *(uint4*)(s_mem + addr) = wd;
        }
    }
    __syncthreads();

    // --- Phase 4: final GEMM 64x256 from LDS tile, wave w -> cols [w*64,+64)
    f32x4 acc[4][4];
#pragma unroll
    for (int i = 0; i < 4; ++i)
#pragma unroll
        for (int j = 0; j < 4; ++j) acc[i][j] = f32x4{0.f, 0.f, 0.f, 0.f};

    const u16* Bw = Wt_out + (size_t)(w * 64) * 256;
#pragma unroll
    for (int ks = 0; ks < 8; ++ks) {
        bf16x8 af[4], bfr[4];
#pragma unroll
        for (int mt = 0; mt < 4; ++mt) {
            const int rm = mt * 16 + lr;
            const int addr = (rm * 512 + ks * 64 + lk8 * 2) ^ ((rm & 7) << 4);
            af[mt] = *(const bf16x8*)(s_mem + addr);
        }
        const int ke = ks * 32 + lk8;
#pragma unroll
        for (int nt = 0; nt < 4; ++nt)
            bfr[nt] = *(const bf16x8*)(Bw + (size_t)(nt * 16 + lr) * 256 + ke);
#pragma unroll
        for (int mt = 0; mt < 4; ++mt)
#pragma unroll
            for (int nt = 0; nt < 4; ++nt)
                acc[mt][nt] = __builtin_amdgcn_mfma_f32_16x16x32_bf16(
                    af[mt], bfr[nt], acc[mt][nt], 0, 0, 0);
    }
#pragma unroll
    for (int nt = 0; nt < 4; ++nt) {
        const int cn = w * 64 + nt * 16 + lr;
        const float bv = b_out[cn];
#pragma unroll
        for (int mt = 0; mt < 4; ++mt)
#pragma unroll
            for (int r4 = 0; r4 < 4; ++r4)
                out[(row0 + mt * 16 + r0 + r4) * 256 + cn] = acc[mt][nt][r4] + bv;
    }
}

// ---------------------------------------------------------------------------
extern "C" void kernel_launch(void* const* d_in, const int* in_sizes, int n_in,
                              void* d_out, int out_size, void* d_ws, size_t ws_size,
                              hipStream_t stream)
{
    const float* x      = (const float*)d_in[0];
    const float* W_in   = (const float*)d_in[1];
    const float* b_in   = (const float*)d_in[2];
    const float* conv_w = (const float*)d_in[3];
    const float* conv_b = (const float*)d_in[4];
    const float* ln_g   = (const float*)d_in[5];
    const float* ln_b   = (const float*)d_in[6];
    const float* W_off  = (const float*)d_in[7];
    const float* b_off  = (const float*)d_in[8];
    const float* W_mask = (const float*)d_in[9];
    const float* b_mask = (const float*)d_in[10];
    const float* W_out  = (const float*)d_in[11];
    const float* b_out  = (const float*)d_in[12];

    // ws layout (~34 MB of 256 MiB):
    //   [0, 16M)      x_feat bf16 [32768][256]
    //   [16M, 32M)    x_proj bf16 [32768][256]
    //   [32M, ...)    Wt_in (128K), Wt_out (128K), Wcomb (24K)
    u16* xfeatb = (u16*)d_ws;
    u16* xprojb = (u16*)((char*)d_ws + 16777216);
    char* wsb   = (char*)d_ws + 33554432;
    u16* Wt_in  = (u16*)(wsb);
    u16* Wt_out = (u16*)(wsb + 131072);
    u16* Wcombp = (u16*)(wsb + 262144);

    prep_w<<<304, 256, 0, stream>>>(W_in, W_out, W_off, W_mask, Wt_in, Wt_out, Wcombp);
    conv_gemm<<<512 + 8192, 256, 0, stream>>>(x, Wt_in, b_in, xprojb,
                                              conv_w, conv_b, ln_g, ln_b, xfeatb);
    offmask_gemm<<<512, 256, 0, stream>>>(xfeatb, xprojb, Wcombp, b_off, b_mask,
                                          Wt_out, b_out, (float*)d_out);
}

// Round 15
// 70.106 us; speedup vs baseline: 1.0367x; 1.0367x over previous
//
#include <hip/hip_runtime.h>
#include <math.h>

// Problem constants
constexpr int LL = 4096;
constexpr int CC = 256;
constexpr int MM = 32768;  // N*L rows

typedef unsigned int u32;
typedef unsigned short u16;
typedef __attribute__((ext_vector_type(8))) short bf16x8;
typedef __attribute__((ext_vector_type(4))) float f32x4;

__device__ __forceinline__ u16 f2b(float f) {   // RNE fp32->bf16
    u32 u = __float_as_uint(f);
    u32 r = (u + 0x7fffu + ((u >> 16) & 1u)) >> 16;
    return (u16)r;
}
__device__ __forceinline__ u32 pack2(float a, float b) {  // RNE pair
    return (u32)f2b(a) | ((u32)f2b(b) << 16);
}

// async global->LDS DMA, 16B per lane; LDS dest = wave-uniform base + lane*16
__device__ __forceinline__ void gl_lds16(const u16* g, u16* l) {
    __builtin_amdgcn_global_load_lds(
        (const __attribute__((address_space(1))) unsigned int*)g,
        (__attribute__((address_space(3))) unsigned int*)l, 16, 0, 0);
}

// ---------------------------------------------------------------------------
// conv_prep: blocks [0,8192): depthwise conv(K=3) + LayerNorm + exact GELU,
// XCD-aligned remap (dispatch d -> sequence d%8). blocks [8192,8496): weights.
// ---------------------------------------------------------------------------
__global__ __launch_bounds__(256) void conv_prep(
    const float* __restrict__ x, const float* __restrict__ cw,
    const float* __restrict__ cbias, const float* __restrict__ lng,
    const float* __restrict__ lnb, u16* __restrict__ xf,
    const float* __restrict__ W_in, const float* __restrict__ W_out,
    const float* __restrict__ W_off, const float* __restrict__ W_mask,
    u16* __restrict__ Wt_in, u16* __restrict__ Wt_out, u16* __restrict__ Wcomb)
{
    const int bid = blockIdx.x;
    const int t = threadIdx.x;
    if (bid >= 8192) {
        const int b = bid - 8192;
        if (b < 256) {
            Wt_in[b * 256 + t]  = f2b(W_in[t * 256 + b]);
            Wt_out[b * 256 + t] = f2b(W_out[t * 256 + b]);
        } else {
            const int j = b - 256;  // 0..47
            const float v = (j < 24) ? W_off[t * 24 + j] : W_mask[t * 24 + (j - 24)];
            Wcomb[j * 256 + t] = f2b(v);
        }
        return;
    }

    // XCD-aligned block remap: i = (bid%8)*1024 + bid/8  (bijective on 8192)
    const int i = ((bid & 7) << 10) | (bid >> 3);

    const int wave = t >> 6;
    const int lane = t & 63;
    const int nl = (i << 2) + wave;
    const int l = nl & (LL - 1);
    const int c0 = lane << 2;
    const size_t base = (size_t)nl * CC + c0;

    float4 xc = *(const float4*)&x[base];
    float4 xm = make_float4(0.f, 0.f, 0.f, 0.f);
    float4 xp = make_float4(0.f, 0.f, 0.f, 0.f);
    if (l > 0)      xm = *(const float4*)&x[base - CC];
    if (l < LL - 1) xp = *(const float4*)&x[base + CC];

    float xmv[4] = {xm.x, xm.y, xm.z, xm.w};
    float xcv[4] = {xc.x, xc.y, xc.z, xc.w};
    float xpv[4] = {xp.x, xp.y, xp.z, xp.w};

    float y[4];
    float sum = 0.f, sq = 0.f;
#pragma unroll
    for (int j = 0; j < 4; ++j) {
        const int c = c0 + j;
        float v = fmaf(xmv[j], cw[c * 3 + 0],
                  fmaf(xcv[j], cw[c * 3 + 1],
                  fmaf(xpv[j], cw[c * 3 + 2], cbias[c])));
        y[j] = v;
        sum += v;
        sq  += v * v;
    }
#pragma unroll
    for (int off = 32; off > 0; off >>= 1) {
        sum += __shfl_xor(sum, off);
        sq  += __shfl_xor(sq, off);
    }
    const float mu  = sum * (1.f / CC);
    const float var = sq * (1.f / CC) - mu * mu;
    const float rs  = rsqrtf(var + 1e-6f);

    ushort4 o;
    float ov[4];
#pragma unroll
    for (int j = 0; j < 4; ++j) {
        const int c = c0 + j;
        const float tn = (y[j] - mu) * rs * lng[c] + lnb[c];
        ov[j] = 0.5f * tn * (1.f + erff(tn * 0.70710678118654752f));
    }
    o.x = f2b(ov[0]); o.y = f2b(ov[1]); o.z = f2b(ov[2]); o.w = f2b(ov[3]);
    *(ushort4*)&xf[base] = o;
}

// ---------------------------------------------------------------------------
// gemm1: x_proj = bf16(x) @ Wt_in^T + b_in (bf16 out), m97 structure:
// 128x128 tile, BK=32, 4 waves, double-buffered LDS. A reg-staged from fp32
// (load-early/write-late); B via global_load_lds. XCD swizzle: XCD k owns
// m-tiles [32k,+32) = sequence n=k -> xproj panel L2-resident on XCD k.
// ---------------------------------------------------------------------------
__global__ __launch_bounds__(256, 2) void gemm1(
    const float* __restrict__ x, const u16* __restrict__ Wt_in,
    const float* __restrict__ b_in, u16* __restrict__ xprojb)
{
    __shared__ u16 As[2][128 * 32];
    __shared__ u16 Bs[2][128 * 32];

    const int t = threadIdx.x;
    const int w = t >> 6, lane = t & 63;
    const int lr = lane & 15, lk = lane >> 4;
    const int wm = w >> 1, wn = w & 1;

    const int d = blockIdx.x;              // 0..511
    const int m_t = (d & 7) * 32 + (d >> 4);
    const int n_t = (d >> 3) & 1;
    const int m0 = m_t * 128, n0 = n_t * 128;

    const int srow = lane >> 2;
    const int scol = (lane & 3) * 8;       // k elements
    const int arow = t >> 1;
    const int akh = (t & 1) * 16;

    f32x4 acc[4][4];
#pragma unroll
    for (int i = 0; i < 4; ++i)
#pragma unroll
        for (int j = 0; j < 4; ++j) acc[i][j] = f32x4{0.f, 0.f, 0.f, 0.f};

    auto STAGE_B = [&](int buf, int kt) {
        const int k0 = kt * 32;
#pragma unroll
        for (int j = 0; j < 2; ++j) {
            const int rr = (w * 2 + j) * 16 + srow;
            gl_lds16(Wt_in + ((size_t)(n0 + rr) << 8) + k0 + scol,
                     &Bs[buf][0] + (w * 2 + j) * 512);
        }
    };
    const float* Abase = x + (size_t)(m0 + arow) * 256 + akh;

    {
        float4 f0 = *(const float4*)(Abase);
        float4 f1 = *(const float4*)(Abase + 4);
        float4 f2 = *(const float4*)(Abase + 8);
        float4 f3 = *(const float4*)(Abase + 12);
        STAGE_B(0, 0);
        u16* dst = &As[0][arow * 32 + akh];
        ((u32*)dst)[0] = pack2(f0.x, f0.y); ((u32*)dst)[1] = pack2(f0.z, f0.w);
        ((u32*)dst)[2] = pack2(f1.x, f1.y); ((u32*)dst)[3] = pack2(f1.z, f1.w);
        ((u32*)dst)[4] = pack2(f2.x, f2.y); ((u32*)dst)[5] = pack2(f2.z, f2.w);
        ((u32*)dst)[6] = pack2(f3.x, f3.y); ((u32*)dst)[7] = pack2(f3.z, f3.w);
    }

#pragma unroll
    for (int kt = 0; kt < 8; ++kt) {
        const int cur = kt & 1;
        __syncthreads();                    // stage of buf[cur] complete
        float4 f0, f1, f2, f3;
        if (kt < 7) {                       // issue next-tile loads EARLY
            const float* ap = Abase + (kt + 1) * 32;
            f0 = *(const float4*)(ap);
            f1 = *(const float4*)(ap + 4);
            f2 = *(const float4*)(ap + 8);
            f3 = *(const float4*)(ap + 12);
            STAGE_B(cur ^ 1, kt + 1);
        }
        bf16x8 af[4], bfr[4];
#pragma unroll
        for (int mt = 0; mt < 4; ++mt)
            af[mt] = *(const bf16x8*)&As[cur][(wm * 64 + mt * 16 + lr) * 32 + lk * 8];
#pragma unroll
        for (int nt = 0; nt < 4; ++nt)
            bfr[nt] = *(const bf16x8*)&Bs[cur][(wn * 64 + nt * 16 + lr) * 32 + lk * 8];
#pragma unroll
        for (int mt = 0; mt < 4; ++mt)
#pragma unroll
            for (int nt = 0; nt < 4; ++nt)
                acc[mt][nt] = __builtin_amdgcn_mfma_f32_16x16x32_bf16(
                    af[mt], bfr[nt], acc[mt][nt], 0, 0, 0);
        if (kt < 7) {                       // write LATE (after MFMAs)
            u16* dst = &As[cur ^ 1][arow * 32 + akh];
            ((u32*)dst)[0] = pack2(f0.x, f0.y); ((u32*)dst)[1] = pack2(f0.z, f0.w);
            ((u32*)dst)[2] = pack2(f1.x, f1.y); ((u32*)dst)[3] = pack2(f1.z, f1.w);
            ((u32*)dst)[4] = pack2(f2.x, f2.y); ((u32*)dst)[5] = pack2(f2.z, f2.w);
            ((u32*)dst)[6] = pack2(f3.x, f3.y); ((u32*)dst)[7] = pack2(f3.z, f3.w);
        }
    }

    const int r0 = lk * 4;
#pragma unroll
    for (int nt = 0; nt < 4; ++nt) {
        const int cn = n0 + wn * 64 + nt * 16 + lr;
        const float bv = b_in[cn];
#pragma unroll
        for (int mt = 0; mt < 4; ++mt)
#pragma unroll
            for (int r4 = 0; r4 < 4; ++r4)
                xprojb[(size_t)(m0 + wm * 64 + mt * 16 + r0 + r4) * 256 + cn] =
                    f2b(acc[mt][nt][r4] + bv);
    }
}

// ---------------------------------------------------------------------------
// offmask_gemm: fused { offset/mask MFMA projection + softmax + bilinear
// gather -> LDS } + { final GEMM sampled@W_out + b_out -> fp32 out }.
// 64-row blocks (512), 256 thr, LDS 44KB, XCD-aligned remap.
// LB(256,2): grid already caps occupancy at 2 blocks/CU; the old LB(256,3)
// only strangled VGPR to 72 and serialized the gather on L2 latency (r4/r5
// disease). With 256-VGPR budget the 48 independent uint4 gather loads and
// P1 fragment loads can pipeline.
// ---------------------------------------------------------------------------
__global__ __launch_bounds__(256, 2) void offmask_gemm(
    const u16* __restrict__ xfeatb, const u16* __restrict__ xprojb,
    const u16* __restrict__ Wcomb, const float* __restrict__ boff,
    const float* __restrict__ bmask, const u16* __restrict__ Wt_out,
    const float* __restrict__ b_out, float* __restrict__ out)
{
    __shared__ __align__(16) char s_mem[32768];   // logit then sampled (union)
    __shared__ uint2 s_pack[512 * 3];             // {fp16 a|b, u16 i0|i1} 12KB
    float* logit = (float*)s_mem;                 // [64][50]

    const int t = threadIdx.x;
    const int w = t >> 6, lane = t & 63;
    const int lr = lane & 15, lk8 = (lane >> 4) * 8;
    const int r0 = (lane >> 4) * 4;
    // XCD-aligned remap: blk = (d%8)*64 + d/8  (bijective on 512)
    const int d = blockIdx.x;
    const int blk = ((d & 7) << 6) | (d >> 3);
    const size_t row0 = (size_t)blk * 64;

    // --- Phase 1: projection MFMA -> logits (48 cols per row)
    f32x4 pacc[3];
#pragma unroll
    for (int ct = 0; ct < 3; ++ct) pacc[ct] = f32x4{0.f, 0.f, 0.f, 0.f};
    const u16* fbase = xfeatb + (row0 + w * 16 + lr) * 256;
#pragma unroll
    for (int ks = 0; ks < 8; ++ks) {
        const int ke = ks * 32 + lk8;
        bf16x8 a = *(const bf16x8*)(fbase + ke);
#pragma unroll
        for (int ct = 0; ct < 3; ++ct) {
            bf16x8 bfr = *(const bf16x8*)(Wcomb + (size_t)(ct * 16 + lr) * 256 + ke);
            pacc[ct] = __builtin_amdgcn_mfma_f32_16x16x32_bf16(a, bfr, pacc[ct], 0, 0, 0);
        }
    }
#pragma unroll
    for (int ct = 0; ct < 3; ++ct) {
        const int j = ct * 16 + lr;
        const float bj = (j < 24) ? boff[j] : bmask[j - 24];
#pragma unroll
        for (int r4 = 0; r4 < 4; ++r4)
            logit[(w * 16 + r0 + r4) * 50 + j] = pacc[ct][r4] + bj;
    }
    __syncthreads();

    // --- Phase 2: softmax over K + locations (2 (row,g) pairs per thread)
#pragma unroll
    for (int pi = 0; pi < 2; ++pi) {
        const int pp = pi * 256 + t;        // 0..511
        const int rw = pp >> 3, g = pp & 7;
        const float* lp = &logit[rw * 50];
        const float m0v = lp[24 + g * 3 + 0];
        const float m1v = lp[24 + g * 3 + 1];
        const float m2v = lp[24 + g * 3 + 2];
        const float mx = fmaxf(m0v, fmaxf(m1v, m2v));
        const float e0 = expf(m0v - mx), e1 = expf(m1v - mx), e2 = expf(m2v - mx);
        const float inv = 1.f / (e0 + e1 + e2);
        const float msk[3] = {e0 * inv, e1 * inv, e2 * inv};
        const float lf = (float)((blk & 63) * 64 + rw);
#pragma unroll
        for (int k = 0; k < 3; ++k) {
            const float loc = lf + (float)(k - 1) + lp[g * 3 + k];
            float r = fmodf(loc, (float)LL);
            if (r < 0.f) r += (float)LL;
            const float f0 = floorf(r);
            int i0 = (int)f0;
            i0 = i0 < 0 ? 0 : (i0 > LL - 1 ? LL - 1 : i0);
            const int i1 = i0 + 1;
            const float w1 = r - f0;
            const bool valid = (i1 < LL);
            union { u32 uw; _Float16 h[2]; } uh;
            uh.h[0] = (_Float16)(msk[k] * (1.f - w1));
            uh.h[1] = (_Float16)(valid ? msk[k] * w1 : 0.f);
            const u32 ij = (u32)i0 | ((u32)(valid ? i1 : 0) << 16);
            s_pack[pp * 3 + k] = make_uint2(uh.uw, ij);
        }
    }
    __syncthreads();   // logit reads done; s_mem reusable as sampled tile

    // --- Phase 3: gather-accumulate -> sampled bf16 tile in LDS (swizzled).
    // 8 row-groups x 32 channel-octs; uint4 loads (8 chans/thread).
    {
        const int ig = t >> 5, tc = t & 31;
        const int c0 = tc * 8, g4 = tc >> 2;
        const u16* xpn = xprojb + (size_t)(blk >> 6) * LL * 256;
        const int ibeg = ig * 8;
#pragma unroll 4
        for (int i = ibeg; i < ibeg + 8; ++i) {
            const int bidx = (i * 8 + g4) * 3;
            float v[8] = {0.f, 0.f, 0.f, 0.f, 0.f, 0.f, 0.f, 0.f};
#pragma unroll
            for (int k = 0; k < 3; ++k) {
                const uint2 pk = s_pack[bidx + k];
                union { u32 uw; _Float16 h[2]; } uh; uh.uw = pk.x;
                const float wa = (float)uh.h[0], wb = (float)uh.h[1];
                const int i0 = (int)(pk.y & 0xffffu), i1 = (int)(pk.y >> 16);
                uint4 ua = *(const uint4*)(xpn + (size_t)i0 * 256 + c0);
                uint4 ub = *(const uint4*)(xpn + (size_t)i1 * 256 + c0);
                const u32 au[4] = {ua.x, ua.y, ua.z, ua.w};
                const u32 bu[4] = {ub.x, ub.y, ub.z, ub.w};
#pragma unroll
                for (int j = 0; j < 4; ++j) {
                    v[2 * j]     = fmaf(wa, __uint_as_float(au[j] << 16),
                                   fmaf(wb, __uint_as_float(bu[j] << 16), v[2 * j]));
                    v[2 * j + 1] = fmaf(wa, __uint_as_float(au[j] & 0xffff0000u),
                                   fmaf(wb, __uint_as_float(bu[j] & 0xffff0000u), v[2 * j + 1]));
                }
            }
            uint4 wd;
            wd.x = pack2(v[0], v[1]); wd.y = pack2(v[2], v[3]);
            wd.z = pack2(v[4], v[5]); wd.w = pack2(v[6], v[7]);
            const int addr = (i * 512 + tc * 16) ^ ((i & 7) << 4);
            *(uint4*)(s_mem + addr) = wd;
        }
    }
    __syncthreads();

    // --- Phase 4: final GEMM 64x256 from LDS tile, wave w -> cols [w*64,+64)
    f32x4 acc[4][4];
#pragma unroll
    for (int i = 0; i < 4; ++i)
#pragma unroll
        for (int j = 0; j < 4; ++j) acc[i][j] = f32x4{0.f, 0.f, 0.f, 0.f};

    const u16* Bw = Wt_out + (size_t)(w * 64) * 256;
#pragma unroll
    for (int ks = 0; ks < 8; ++ks) {
        bf16x8 af[4], bfr[4];
#pragma unroll
        for (int mt = 0; mt < 4; ++mt) {
            const int rm = mt * 16 + lr;
            const int addr = (rm * 512 + ks * 64 + lk8 * 2) ^ ((rm & 7) << 4);
            af[mt] = *(const bf16x8*)(s_mem + addr);
        }
        const int ke = ks * 32 + lk8;
#pragma unroll
        for (int nt = 0; nt < 4; ++nt)
            bfr[nt] = *(const bf16x8*)(Bw + (size_t)(nt * 16 + lr) * 256 + ke);
#pragma unroll
        for (int mt = 0; mt < 4; ++mt)
#pragma unroll
            for (int nt = 0; nt < 4; ++nt)
                acc[mt][nt] = __builtin_amdgcn_mfma_f32_16x16x32_bf16(
                    af[mt], bfr[nt], acc[mt][nt], 0, 0, 0);
    }
#pragma unroll
    for (int nt = 0; nt < 4; ++nt) {
        const int cn = w * 64 + nt * 16 + lr;
        const float bv = b_out[cn];
#pragma unroll
        for (int mt = 0; mt < 4; ++mt)
#pragma unroll
            for (int r4 = 0; r4 < 4; ++r4)
                out[(row0 + mt * 16 + r0 + r4) * 256 + cn] = acc[mt][nt][r4] + bv;
    }
}

// ---------------------------------------------------------------------------
extern "C" void kernel_launch(void* const* d_in, const int* in_sizes, int n_in,
                              void* d_out, int out_size, void* d_ws, size_t ws_size,
                              hipStream_t stream)
{
    const float* x      = (const float*)d_in[0];
    const float* W_in   = (const float*)d_in[1];
    const float* b_in   = (const float*)d_in[2];
    const float* conv_w = (const float*)d_in[3];
    const float* conv_b = (const float*)d_in[4];
    const float* ln_g   = (const float*)d_in[5];
    const float* ln_b   = (const float*)d_in[6];
    const float* W_off  = (const float*)d_in[7];
    const float* b_off  = (const float*)d_in[8];
    const float* W_mask = (const float*)d_in[9];
    const float* b_mask = (const float*)d_in[10];
    const float* W_out  = (const float*)d_in[11];
    const float* b_out  = (const float*)d_in[12];

    // ws layout (~34 MB of 256 MiB):
    //   [0, 16M)      x_feat bf16 [32768][256]
    //   [16M, 32M)    x_proj bf16 [32768][256]
    //   [32M, ...)    Wt_in (128K), Wt_out (128K), Wcomb (24K)
    u16* xfeatb = (u16*)d_ws;
    u16* xprojb = (u16*)((char*)d_ws + 16777216);
    char* wsb   = (char*)d_ws + 33554432;
    u16* Wt_in  = (u16*)(wsb);
    u16* Wt_out = (u16*)(wsb + 131072);
    u16* Wcombp = (u16*)(wsb + 262144);

    conv_prep<<<8192 + 304, 256, 0, stream>>>(x, conv_w, conv_b, ln_g, ln_b, xfeatb,
                                              W_in, W_out, W_off, W_mask,
                                              Wt_in, Wt_out, Wcombp);
    gemm1<<<512, 256, 0, stream>>>(x, Wt_in, b_in, xprojb);
    offmask_gemm<<<512, 256, 0, stream>>>(xfeatb, xprojb, Wcombp, b_off, b_mask,
                                          Wt_out, b_out, (float*)d_out);
}